// Round 3
// 216.512 us; speedup vs baseline: 1.0077x; 1.0077x over previous
//
#include <hip/hip_runtime.h>

// SoftEmbeddedDecisionRules: balanced binary hierarchy over C=1024 classes.
// out[b,c] = prod over 10 levels of softmax-over-2-children prob of the branch
// containing c, where child logit = mean of raw logits over the child's block.
// softmax over 2 == sigmoid(diff of means). Barrier-free tree:
//   - seg=1,2 levels in registers (float4 per thread)
//   - seg=4..128 levels via 6-step __shfl_xor butterfly inside each wave:
//     at step k my running sum covers my 4k-class block and the partner lane's
//     sum covers the sibling block, so p(my branch)=sigmoid((partner-mine)/seg)
//   - seg=256,512 levels from the 4 wave totals (16B LDS, ONE __syncthreads)
// vs previous version: 9 barriers + 768B LDS heap + 11 full-precision divides
// -> 1 barrier + 16B LDS + fast v_rcp_f32.

#define C 1024

__device__ __forceinline__ float sigmoid_of(float x) {
    // 1 / (1 + exp(x)) ; v_rcp_f32 approx (~1e-7 rel err, absmax budget 3e-5)
    return __builtin_amdgcn_rcpf(1.0f + __expf(x));
}

__global__ __launch_bounds__(256) void hier_softmax_kernel(
    const float* __restrict__ in, float* __restrict__ out) {
    __shared__ float wsum[4];  // per-wave totals (256 classes each)

    const int row = blockIdx.x;
    const int tid = threadIdx.x;
    const int wave = tid >> 6;
    const int lane = tid & 63;

    const float4 v = ((const float4*)(in + (size_t)row * C))[tid];

    // bottom two levels in registers
    const float s2a = v.x + v.y;            // seg=2 pair sums
    const float s2b = v.z + v.w;
    float sum = s2a + s2b;                  // seg=4 block sum (this thread's block)

    const float pA = sigmoid_of(v.y - v.x);            // seg=1 level, left pair
    const float pB = sigmoid_of(v.w - v.z);            // seg=1 level, right pair
    const float p9 = sigmoid_of((s2b - s2a) * 0.5f);   // seg=2 level

    // seg=4..128 levels: butterfly within wave. At step k, `sum` covers the
    // 4k-class block containing this thread's classes; partner lane (tid^k)
    // holds the sibling block's sum. Multiply in p(my branch) each step.
    float common = 1.0f;
    float inv_seg = 0.25f;
#pragma unroll
    for (int k = 1; k <= 32; k <<= 1) {
        const float partner = __shfl_xor(sum, k, 64);
        common *= sigmoid_of((partner - sum) * inv_seg);
        sum += partner;
        inv_seg *= 0.5f;
    }
    // sum == this wave's 256-class total

    if (lane == 0) wsum[wave] = sum;
    __syncthreads();  // the only barrier

    // seg=256 level: sibling wave's total
    const float partnerW = wsum[wave ^ 1];
    common *= sigmoid_of((partnerW - sum) * (1.0f / 256.0f));
    // seg=512 level (root): my half vs other half
    const float myHalf = sum + partnerW;
    const float otherHalf = wsum[wave ^ 2] + wsum[wave ^ 3];
    common *= sigmoid_of((otherHalf - myHalf) * (1.0f / 512.0f));

    // fold in the register levels and store
    const float cl = common * p9;
    const float cr = common - cl;   // common * (1 - p9)
    float4 o;
    o.x = cl * pA;
    o.y = cl - o.x;                 // cl * (1 - pA)
    o.z = cr * pB;
    o.w = cr - o.z;                 // cr * (1 - pB)
    ((float4*)(out + (size_t)row * C))[tid] = o;
}

extern "C" void kernel_launch(void* const* d_in, const int* in_sizes, int n_in,
                              void* d_out, int out_size, void* d_ws, size_t ws_size,
                              hipStream_t stream) {
    const float* in = (const float*)d_in[0];
    float* out = (float*)d_out;
    const int B = in_sizes[0] / C;  // 32768
    hier_softmax_kernel<<<B, 256, 0, stream>>>(in, out);
}